// Round 3
// baseline (309.303 us; speedup 1.0000x reference)
//
#include <hip/hip_runtime.h>

// K1: f[n][t] = exp(-dot(w[t,n,0,:], ev[t,n,:]) * time[t&1])
//     one wave per (t,t+1,n) pair of dots -> 25600 waves, coalesced float4.
// K2: 100-step scan; per block (nb,h): 128 chains. a-data staged in LDS
//     chunks of CH=10 steps (30 KB) via global_load_lds (bulk, double buffer).
//
// Layouts: event_list[201,256,256], a[200,256,256,3], w[200,256,1,256],
//          u_begin[256,256,3], liner_w[256,3], liner_b[256], out[100,256,256].

#define NN 256
#define TT 200
#define SS 100
#define CH 10                    // steps per chunk
#define SLABS (2*CH)             // 20 t-slabs per chunk
#define HALF 128                 // threads per scan block (half of row n)
#define SEG (HALF*3)             // 384 floats: this block's share of one t-slab
#define CHUNKF (SLABS*SEG)       // 7680 floats per chunk buffer
#define NCHUNK (SS/CH)           // 10

typedef const __attribute__((address_space(1))) void* gas1;
typedef __attribute__((address_space(3))) void* las3;

__global__ __launch_bounds__(256) void f_kernel(
    const float* __restrict__ timep,
    const float* __restrict__ ev,
    const float* __restrict__ w,
    float* __restrict__ fs)          // [N,T] transposed
{
    const int lane  = threadIdx.x & 63;
    const int gwave = blockIdx.x * 4 + (threadIdx.x >> 6);
    const int n  = gwave & 255;
    const int tp = gwave >> 8;       // [0,100)
    const int ta = 2 * tp;

    const size_t ro_a = (size_t)ta * (NN * NN) + (size_t)n * NN;
    const size_t ro_b = ro_a + (size_t)(NN * NN);
    float4 wa = ((const float4*)(w  + ro_a))[lane];
    float4 ea = ((const float4*)(ev + ro_a))[lane];
    float4 wb = ((const float4*)(w  + ro_b))[lane];
    float4 eb = ((const float4*)(ev + ro_b))[lane];
    float da = wa.x * ea.x;
    da = fmaf(wa.y, ea.y, da); da = fmaf(wa.z, ea.z, da); da = fmaf(wa.w, ea.w, da);
    float db = wb.x * eb.x;
    db = fmaf(wb.y, eb.y, db); db = fmaf(wb.z, eb.z, db); db = fmaf(wb.w, eb.w, db);
#pragma unroll
    for (int off = 1; off < 64; off <<= 1) {
        da += __shfl_xor(da, off, 64);
        db += __shfl_xor(db, off, 64);
    }
    if (lane == 0) {
        float2 r;
        r.x = __expf(-da * timep[0]);   // even t -> time[0]
        r.y = __expf(-db * timep[1]);   // odd t  -> time[1]
        ((float2*)(fs + (size_t)n * TT))[tp] = r;
    }
}

__global__ __launch_bounds__(HALF) void scan_kernel(
    const float* __restrict__ fs_g,   // [N,T]
    const float* __restrict__ ub,     // [N,N,3]
    const float* __restrict__ a,      // [T,N,N,3]
    const float* __restrict__ lw,     // [N,3]
    const float* __restrict__ lb,     // [N]
    float* __restrict__ out)          // [S,N,N]
{
    __shared__ float fs[TT];
    __shared__ float buf[2][CHUNKF];  // 2 x 30720 B

    const int nb   = blockIdx.x >> 1;
    const int h    = blockIdx.x & 1;
    const int mm   = threadIdx.x;     // 0..127
    const int lane = mm & 63;
    const int wid  = mm >> 6;         // 0..1

    if (mm < TT) fs[mm] = fs_g[(size_t)nb * TT + mm];
    if (mm + HALF < TT) fs[mm + HALF] = fs_g[(size_t)nb * TT + mm + HALF];

    const size_t rowbase = (size_t)nb * 768 + (size_t)h * SEG;  // float offset of this block's SEG within a t-slab
    const size_t TS = (size_t)NN * NN * 3;                      // 196608 floats per t

    // one chunk = SLABS slab-segments of SEG floats = 1920 float4 = 30 wave-rounds
    auto fill = [&](int c, int which) {
#pragma unroll
        for (int r = 0; r < 15; ++r) {
            const unsigned base4 = (unsigned)((r * 2 + wid) * 64);  // wave-uniform float4 idx
            const unsigned q  = base4 + (unsigned)lane;             // per-lane float4 idx [0,1920)
            const unsigned tl = q / 96;                             // slab (96 float4 per SEG)
            const unsigned o4 = q - tl * 96;
            const float* g = a + (size_t)(c * SLABS + tl) * TS + rowbase + (size_t)o4 * 4;
            float* l = &buf[which][(size_t)base4 * 4];              // HW adds lane*16B
            __builtin_amdgcn_global_load_lds((gas1)g, (las3)l, 16, 0, 0);
        }
    };

    fill(0, 0);

    float u0, u1, u2;
    {
        const size_t b = rowbase + (size_t)mm * 3;
        u0 = ub[b + 0]; u1 = ub[b + 1]; u2 = ub[b + 2];
    }
    const float w0 = lw[nb * 3 + 0];
    const float w1 = lw[nb * 3 + 1];
    const float w2 = lw[nb * 3 + 2];
    const float bbias = lb[nb];
    float* op = out + (size_t)nb * NN + (size_t)h * HALF + mm;

    __syncthreads();   // drains fill(0) + fs loads

    for (int c = 0; c < NCHUNK; ++c) {
        if (c + 1 < NCHUNK) fill(c + 1, (c + 1) & 1);   // stream next chunk while computing
        const float* B = buf[c & 1];
#pragma unroll
        for (int k = 0; k < CH; ++k) {
            const int s = c * CH + k;
            const float* s0 = B + (size_t)(2 * k) * SEG + (size_t)mm * 3;
            const float* s1 = s0 + SEG;
            const float f0 = fs[2 * s];
            const float f1 = fs[2 * s + 1];
            float l0 = fmaf(s0[0], f0, fmaf(s1[0], f1, u0));
            float l1 = fmaf(s0[1], f0, fmaf(s1[1], f1, u1));
            float l2 = fmaf(s0[2], f0, fmaf(s1[2], f1, u2));
            float mx = fmaxf(l0, fmaxf(l1, l2));
            float e0 = __expf(l0 - mx);
            float e1 = __expf(l1 - mx);
            float e2 = __expf(l2 - mx);
            float inv = __builtin_amdgcn_rcpf(e0 + e1 + e2);
            u0 = e0 * inv; u1 = e1 * inv; u2 = e2 * inv;
            op[(size_t)s * (NN * NN)] = fmaf(u0, w0, fmaf(u1, w1, fmaf(u2, w2, bbias)));
        }
        __syncthreads();  // drains fill(c+1); releases buf[c&1] for overwrite
    }
}

extern "C" void kernel_launch(void* const* d_in, const int* in_sizes, int n_in,
                              void* d_out, int out_size, void* d_ws, size_t ws_size,
                              hipStream_t stream) {
    const float* timep = (const float*)d_in[0];
    const float* ev    = (const float*)d_in[1];
    const float* ub    = (const float*)d_in[2];
    const float* a     = (const float*)d_in[3];
    const float* w     = (const float*)d_in[4];
    const float* lw    = (const float*)d_in[5];
    const float* lb    = (const float*)d_in[6];
    float* out = (float*)d_out;
    float* fs  = (float*)d_ws;        // [256,200] f32 = 204800 B

    // K1: 25600 waves (one per t-pair x n) = 6400 blocks x 4 waves
    f_kernel<<<(SS * NN) / 4, 256, 0, stream>>>(timep, ev, w, fs);
    // K2: 512 blocks (2 per n), 128 threads each -> 2 blocks/CU
    scan_kernel<<<2 * NN, HALF, 0, stream>>>(fs, ub, a, lw, lb, out);
}

// Round 4
// 307.104 us; speedup vs baseline: 1.0072x; 1.0072x over previous
//
#include <hip/hip_runtime.h>

// K1: f[n][t] = exp(-dot(w[t,n,0,:], ev[t,n,:]) * time[t&1])
//     one wave per (t,t+1,n) dot-pair -> 25600 waves, coalesced float4.
// K2: scan with HIGH WAVE COUNT: 1024 blocks x 256 threads, 64 chains/block.
//     All 4 waves stage a-data (plain float4 loads -> regs -> ds_write,
//     double-buffered LDS); wave 0 computes the 64 chains. ~5 blocks/CU
//     (31.5 KB LDS) -> 20 waves/CU staging concurrently.
//
// Layouts: event_list[201,256,256], a[200,256,256,3], w[200,256,1,256],
//          u_begin[256,256,3], liner_w[256,3], liner_b[256], out[100,256,256].

#define NN 256
#define TT 200
#define SS 100
#define CH 10                   // steps per chunk
#define SLABS (2*CH)            // 20 t-slabs per chunk
#define NCH 64                  // chains per block
#define SLAB_F (NCH*3)          // 192 floats: block's share of one t-slab
#define CHUNK_F (SLABS*SLAB_F)  // 3840 floats per buffer
#define CHUNK_F4 (CHUNK_F/4)    // 960 float4
#define NCHUNK (SS/CH)          // 10

__global__ __launch_bounds__(256) void f_kernel(
    const float* __restrict__ timep,
    const float* __restrict__ ev,
    const float* __restrict__ w,
    float* __restrict__ fs)          // [N,T] transposed
{
    const int lane  = threadIdx.x & 63;
    const int gwave = blockIdx.x * 4 + (threadIdx.x >> 6);
    const int n  = gwave & 255;
    const int tp = gwave >> 8;       // [0,100)

    const size_t ro_a = (size_t)(2 * tp) * (NN * NN) + (size_t)n * NN;
    const size_t ro_b = ro_a + (size_t)(NN * NN);
    float4 wa = ((const float4*)(w  + ro_a))[lane];
    float4 ea = ((const float4*)(ev + ro_a))[lane];
    float4 wb = ((const float4*)(w  + ro_b))[lane];
    float4 eb = ((const float4*)(ev + ro_b))[lane];
    float da = wa.x * ea.x;
    da = fmaf(wa.y, ea.y, da); da = fmaf(wa.z, ea.z, da); da = fmaf(wa.w, ea.w, da);
    float db = wb.x * eb.x;
    db = fmaf(wb.y, eb.y, db); db = fmaf(wb.z, eb.z, db); db = fmaf(wb.w, eb.w, db);
#pragma unroll
    for (int off = 1; off < 64; off <<= 1) {
        da += __shfl_xor(da, off, 64);
        db += __shfl_xor(db, off, 64);
    }
    if (lane == 0) {
        float2 r;
        r.x = __expf(-da * timep[0]);   // even t -> time[0]
        r.y = __expf(-db * timep[1]);   // odd t  -> time[1]
        ((float2*)(fs + (size_t)n * TT))[tp] = r;
    }
}

__global__ __launch_bounds__(256) void scan_kernel(
    const float* __restrict__ fs_g,   // [N,T]
    const float* __restrict__ ub,     // [N,N,3]
    const float* __restrict__ a,      // [T,N,N,3]
    const float* __restrict__ lw,     // [N,3]
    const float* __restrict__ lb,     // [N]
    float* __restrict__ out)          // [S,N,N]
{
    __shared__ float fs[TT];
    __shared__ float buf[2][CHUNK_F];   // 2 x 15360 B

    const int nb  = blockIdx.x >> 2;    // row n
    const int qt  = blockIdx.x & 3;     // quarter of the row
    const int tid = threadIdx.x;

    if (tid < TT) fs[tid] = fs_g[(size_t)nb * TT + tid];

    const size_t rowbase = (size_t)nb * 768 + (size_t)qt * SLAB_F; // float off within a t-slab
    const size_t TS = (size_t)NN * NN * 3;                         // 196608 floats per t

    // ---- staging helpers: 960 float4 per chunk, 256 threads -> 4 rounds ----
    float4 pf0, pf1, pf2, pf3;
    auto load_chunk = [&](int c) {
        const int q0 = tid, q1 = tid + 256, q2 = tid + 512, q3 = tid + 768;
        {
            const int tl = q0 / 48, o4 = q0 - tl * 48;
            pf0 = *(const float4*)(a + (size_t)(c * SLABS + tl) * TS + rowbase + (size_t)o4 * 4);
        }
        {
            const int tl = q1 / 48, o4 = q1 - tl * 48;
            pf1 = *(const float4*)(a + (size_t)(c * SLABS + tl) * TS + rowbase + (size_t)o4 * 4);
        }
        {
            const int tl = q2 / 48, o4 = q2 - tl * 48;
            pf2 = *(const float4*)(a + (size_t)(c * SLABS + tl) * TS + rowbase + (size_t)o4 * 4);
        }
        if (q3 < CHUNK_F4) {
            const int tl = q3 / 48, o4 = q3 - tl * 48;
            pf3 = *(const float4*)(a + (size_t)(c * SLABS + tl) * TS + rowbase + (size_t)o4 * 4);
        }
    };
    auto store_chunk = [&](int which) {
        float4* B = (float4*)buf[which];
        B[tid]       = pf0;
        B[tid + 256] = pf1;
        B[tid + 512] = pf2;
        if (tid + 768 < CHUNK_F4) B[tid + 768] = pf3;
    };

    // chain state (wave 0 only)
    float u0 = 0.f, u1 = 0.f, u2 = 0.f, w0 = 0.f, w1 = 0.f, w2 = 0.f, bbias = 0.f;
    float* op = out;
    if (tid < NCH) {
        const size_t b = rowbase + (size_t)tid * 3;
        u0 = ub[b + 0]; u1 = ub[b + 1]; u2 = ub[b + 2];
        w0 = lw[nb * 3 + 0]; w1 = lw[nb * 3 + 1]; w2 = lw[nb * 3 + 2];
        bbias = lb[nb];
        op = out + (size_t)nb * NN + (size_t)qt * NCH + tid;
    }

    // prologue: stage chunk 0
    load_chunk(0);
    store_chunk(0);
    __syncthreads();

    for (int c = 0; c < NCHUNK; ++c) {
        if (c + 1 < NCHUNK) load_chunk(c + 1);   // issue next chunk's global loads

        if (tid < NCH) {
            const float* B = buf[c & 1];
#pragma unroll
            for (int k = 0; k < CH; ++k) {
                const int s = c * CH + k;
                const float* s0 = B + (size_t)(2 * k) * SLAB_F + (size_t)tid * 3;
                const float* s1 = s0 + SLAB_F;
                const float f0 = fs[2 * s];
                const float f1 = fs[2 * s + 1];
                float l0 = fmaf(s0[0], f0, fmaf(s1[0], f1, u0));
                float l1 = fmaf(s0[1], f0, fmaf(s1[1], f1, u1));
                float l2 = fmaf(s0[2], f0, fmaf(s1[2], f1, u2));
                float mx = fmaxf(l0, fmaxf(l1, l2));
                float e0 = __expf(l0 - mx);
                float e1 = __expf(l1 - mx);
                float e2 = __expf(l2 - mx);
                float inv = __builtin_amdgcn_rcpf(e0 + e1 + e2);
                u0 = e0 * inv; u1 = e1 * inv; u2 = e2 * inv;
                op[(size_t)s * (NN * NN)] = fmaf(u0, w0, fmaf(u1, w1, fmaf(u2, w2, bbias)));
            }
        }

        if (c + 1 < NCHUNK) store_chunk((c + 1) & 1);  // regs -> other LDS buffer
        __syncthreads();
    }
}

extern "C" void kernel_launch(void* const* d_in, const int* in_sizes, int n_in,
                              void* d_out, int out_size, void* d_ws, size_t ws_size,
                              hipStream_t stream) {
    const float* timep = (const float*)d_in[0];
    const float* ev    = (const float*)d_in[1];
    const float* ub    = (const float*)d_in[2];
    const float* a     = (const float*)d_in[3];
    const float* w     = (const float*)d_in[4];
    const float* lw    = (const float*)d_in[5];
    const float* lb    = (const float*)d_in[6];
    float* out = (float*)d_out;
    float* fs  = (float*)d_ws;        // [256,200] f32 = 204800 B

    // K1: 25600 waves (one per t-pair x n) = 6400 blocks x 4 waves
    f_kernel<<<(SS * NN) / 4, 256, 0, stream>>>(timep, ev, w, fs);
    // K2: 1024 blocks (4 per n), 256 threads, 64 chains each -> ~20 waves/CU
    scan_kernel<<<4 * NN, 256, 0, stream>>>(fs, ub, a, lw, lb, out);
}